// Round 5
// baseline (70.489 us; speedup 1.0000x reference)
//
#include <hip/hip_runtime.h>

// Problem geometry (fixed by reference):
//   preds : (B=2, T=8, E=16, H=128, W=256) f32, idx ((b*8+t)*16+e)*HW + hw
//   target: (B=2, T=8, 1,    H=128, W=256) f32
//   output: scalar f32
#define HW    32768   // 128*256
#define T_DIM 8
#define E_DIM 16
#define NPOS  65536   // B * HW
#define BLK   256
#define NTHREADS (NPOS * T_DIM)     // 524288: one thread per (b,t,hw)
#define NBLK  (NTHREADS / BLK)      // 2048

// One thread per (b,t,hw); t lives in the low 3 lane bits so the thread
// holding (b,t-1,hw) is lane-1 -> temporal diffs via __shfl, every element
// loaded exactly once. Single dispatch: last block reduces the partials.
__global__ __launch_bounds__(BLK, 8) void crps_fused(const float* __restrict__ preds,
                                                     const float* __restrict__ target,
                                                     float* __restrict__ partials,
                                                     unsigned int* __restrict__ counter,
                                                     float* __restrict__ out) {
    const int n  = blockIdx.x * BLK + threadIdx.x;   // 19 bits
    const int t  = n & 7;                            // lane bits [0,3)
    const int hw = (n >> 3) & (HW - 1);
    const int b  = n >> 18;

    const float* pb = preds + (size_t)((b * T_DIM + t) * E_DIM) * HW + hw;
    float cur[E_DIM];
#pragma unroll
    for (int e = 0; e < E_DIM; ++e)
        cur[e] = pb[(size_t)e * HW];
    const float tgt = target[(size_t)(b * T_DIM + t) * HW + hw];

    // temporal transition (t-1 -> t): pull previous-t value from lane-1
    const int lane = threadIdx.x & 63;
    float tacc = 0.f;
#pragma unroll
    for (int e = 0; e < E_DIM; ++e) {
        float pv = __shfl(cur[e], lane - 1, 64);     // wraps for lane 0; guarded
        if (t > 0)
            tacc += fabsf(cur[e] - pv);
    }

    // term1: sum_e |p_e - tgt|
    float t1 = 0.f;
#pragma unroll
    for (int e = 0; e < E_DIM; ++e)
        t1 += fabsf(cur[e] - tgt);
    // term2 core: sum_{i<j} |p_i - p_j|
    float s = 0.f;
#pragma unroll
    for (int i = 0; i < E_DIM; ++i)
#pragma unroll
        for (int j = i + 1; j < E_DIM; ++j)
            s += fabsf(cur[i] - cur[j]);

    // contribution of this (b,t,hw)
    float v = (t1 * (1.f / 16.f) - s * (1.f / 256.f)) * (1.f / 8.f)
            + tacc * (0.1f / 112.f);

    // block reduction
    __shared__ float rlds[4];
#pragma unroll
    for (int off = 32; off; off >>= 1)
        v += __shfl_down(v, off, 64);
    const int wid = threadIdx.x >> 6;
    if (lane == 0) rlds[wid] = v;
    __syncthreads();
    float bsum = rlds[0] + rlds[1] + rlds[2] + rlds[3];

    // publish partial + arrive
    __shared__ bool is_last;
    if (threadIdx.x == 0) {
        __hip_atomic_store(&partials[blockIdx.x], bsum,
                           __ATOMIC_RELAXED, __HIP_MEMORY_SCOPE_AGENT);
        unsigned int old = __hip_atomic_fetch_add(counter, 1u,
                           __ATOMIC_ACQ_REL, __HIP_MEMORY_SCOPE_AGENT);
        is_last = (old == NBLK - 1);
    }
    __syncthreads();

    if (is_last) {
        __threadfence();                             // acquire: no stale L2
        float v2 = 0.f;
#pragma unroll
        for (int i = 0; i < NBLK / BLK; ++i)         // 8 partials per thread
            v2 += __hip_atomic_load(&partials[i * BLK + threadIdx.x],
                                    __ATOMIC_RELAXED, __HIP_MEMORY_SCOPE_AGENT);
        __shared__ float flds[4];
#pragma unroll
        for (int off = 32; off; off >>= 1)
            v2 += __shfl_down(v2, off, 64);
        if (lane == 0) flds[wid] = v2;
        __syncthreads();
        if (threadIdx.x == 0)
            out[0] = (flds[0] + flds[1] + flds[2] + flds[3]) * (1.f / (float)NPOS);
    }
}

extern "C" void kernel_launch(void* const* d_in, const int* in_sizes, int n_in,
                              void* d_out, int out_size, void* d_ws, size_t ws_size,
                              hipStream_t stream) {
    const float* preds  = (const float*)d_in[0];
    const float* target = (const float*)d_in[1];
    float* out = (float*)d_out;

    float*        partials = (float*)d_ws;                    // 2048 f32 = 8 KB
    unsigned int* counter  = (unsigned int*)((char*)d_ws + NBLK * sizeof(float));

    hipMemsetAsync(counter, 0, sizeof(unsigned int), stream); // graph-capturable
    crps_fused<<<NBLK, BLK, 0, stream>>>(preds, target, partials, counter, out);
}

// Round 6
// 42.847 us; speedup vs baseline: 1.6451x; 1.6451x over previous
//
#include <hip/hip_runtime.h>

// Problem geometry (fixed by reference):
//   preds : (B=2, T=8, E=16, H=128, W=256) f32, idx ((b*8+t)*16+e)*HW + hw
//   target: (B=2, T=8, 1,    H=128, W=256) f32
//   output: scalar f32
#define HW    32768   // 128*256
#define T_DIM 8
#define E_DIM 16
#define NPOS  65536   // B * HW
#define BLK   256
#define NTHREADS 262144             // B * HW * 4 t-pairs
#define NBLK  (NTHREADS / BLK)      // 1024

// term1/16 - term2core/256 for one (b,t,hw): p[16] vs tgt
__device__ __forceinline__ float crps_term(const float* p, float tgt) {
    float t1 = 0.f;
#pragma unroll
    for (int e = 0; e < E_DIM; ++e)
        t1 += fabsf(p[e] - tgt);
    float s = 0.f;
#pragma unroll
    for (int i = 0; i < E_DIM; ++i)
#pragma unroll
        for (int j = i + 1; j < E_DIM; ++j)
            s += fabsf(p[i] - p[j]);
    return t1 * (1.f / 16.f) - s * (1.f / 256.f);
}

// Thread (b, hw, k) owns t in {2k, 2k+1}; k lives in the low 2 lane bits so
// the thread holding pair k-1 (same hw) is lane-1 -> boundary temporal diffs
// via __shfl. Every preds/target element is loaded exactly once. Single
// dispatch: last arriving block reduces the 1024 partials.
// NOTE: no forced min-occupancy — R5 showed __launch_bounds__(256,8) makes
// the allocator spill cur[] to scratch (VGPR=20, 5x regression).
__global__ __launch_bounds__(BLK) void crps_fused(const float* __restrict__ preds,
                                                  const float* __restrict__ target,
                                                  float* __restrict__ partials,
                                                  unsigned int* __restrict__ counter,
                                                  float* __restrict__ out) {
    const int n  = blockIdx.x * BLK + threadIdx.x;   // 18 bits
    const int k  = n & 3;                            // t-pair 0..3 (lane bits)
    const int hw = (n >> 2) & (HW - 1);              // 15 bits
    const int b  = n >> 17;                          // 0..1
    const int t0 = 2 * k;

    const float* pb = preds  + hw;
    const float* tb = target + hw;

    float cur0[E_DIM], cur1[E_DIM];
#pragma unroll
    for (int e = 0; e < E_DIM; ++e)
        cur0[e] = pb[((size_t)((b * T_DIM + t0) * E_DIM) + e) * HW];
#pragma unroll
    for (int e = 0; e < E_DIM; ++e)
        cur1[e] = pb[((size_t)((b * T_DIM + t0 + 1) * E_DIM) + e) * HW];
    const float tgt0 = tb[(size_t)(b * T_DIM + t0) * HW];
    const float tgt1 = tb[(size_t)(b * T_DIM + t0 + 1) * HW];

    // boundary transition t=2k-1 -> 2k: pull neighbor lane's cur1
    const int lane = threadIdx.x & 63;
    const int src  = (lane > 0) ? (lane - 1) : 0;
    float tacc = 0.f;
#pragma unroll
    for (int e = 0; e < E_DIM; ++e) {
        float pv = __shfl(cur1[e], src, 64);         // exec-sync, DS pipe
        if (k > 0)
            tacc += fabsf(cur0[e] - pv);
    }
    // within-pair transition t=2k -> 2k+1
#pragma unroll
    for (int e = 0; e < E_DIM; ++e)
        tacc += fabsf(cur1[e] - cur0[e]);

    float acc = crps_term(cur0, tgt0) + crps_term(cur1, tgt1);

    // per-(b,hw) scaling: crps terms averaged over 8 t; temporal over 112
    float v = acc * (1.f / 8.f) + tacc * (0.1f / 112.f);

    // block reduction
    __shared__ float rlds[4];
#pragma unroll
    for (int off = 32; off; off >>= 1)
        v += __shfl_down(v, off, 64);
    const int wid = threadIdx.x >> 6;
    if (lane == 0) rlds[wid] = v;
    __syncthreads();
    float bsum = rlds[0] + rlds[1] + rlds[2] + rlds[3];

    // publish partial + arrive
    __shared__ bool is_last;
    if (threadIdx.x == 0) {
        __hip_atomic_store(&partials[blockIdx.x], bsum,
                           __ATOMIC_RELAXED, __HIP_MEMORY_SCOPE_AGENT);
        unsigned int old = __hip_atomic_fetch_add(counter, 1u,
                           __ATOMIC_ACQ_REL, __HIP_MEMORY_SCOPE_AGENT);
        is_last = (old == NBLK - 1);
    }
    __syncthreads();

    if (is_last) {
        __threadfence();                             // acquire: no stale L2
        float v2 = 0.f;
#pragma unroll
        for (int i = 0; i < NBLK / BLK; ++i)         // 4 partials per thread
            v2 += __hip_atomic_load(&partials[i * BLK + threadIdx.x],
                                    __ATOMIC_RELAXED, __HIP_MEMORY_SCOPE_AGENT);
        __shared__ float flds[4];
#pragma unroll
        for (int off = 32; off; off >>= 1)
            v2 += __shfl_down(v2, off, 64);
        if (lane == 0) flds[wid] = v2;
        __syncthreads();
        if (threadIdx.x == 0)
            out[0] = (flds[0] + flds[1] + flds[2] + flds[3]) * (1.f / (float)NPOS);
    }
}

extern "C" void kernel_launch(void* const* d_in, const int* in_sizes, int n_in,
                              void* d_out, int out_size, void* d_ws, size_t ws_size,
                              hipStream_t stream) {
    const float* preds  = (const float*)d_in[0];
    const float* target = (const float*)d_in[1];
    float* out = (float*)d_out;

    float*        partials = (float*)d_ws;                    // 1024 f32 = 4 KB
    unsigned int* counter  = (unsigned int*)((char*)d_ws + NBLK * sizeof(float));

    hipMemsetAsync(counter, 0, sizeof(unsigned int), stream); // graph-capturable
    crps_fused<<<NBLK, BLK, 0, stream>>>(preds, target, partials, counter, out);
}

// Round 7
// 16.641 us; speedup vs baseline: 4.2360x; 2.5749x over previous
//
#include <hip/hip_runtime.h>

// Problem geometry (fixed by reference):
//   preds : (B=2, T=8, E=16, H=128, W=256) f32, idx ((b*8+t)*16+e)*HW + hw
//   target: (B=2, T=8, 1,    H=128, W=256) f32
//   output: scalar f32
#define HW    32768   // 128*256
#define T_DIM 8
#define E_DIM 16
#define NPOS  65536   // B * HW
#define BLK   256
#define NTHREADS (NPOS * T_DIM)     // 524288: one thread per (b,t,hw)
#define NBLK  (NTHREADS / BLK)      // 2048

__device__ __forceinline__ float block_reduce_256(float v, float* lds) {
#pragma unroll
    for (int off = 32; off; off >>= 1)
        v += __shfl_down(v, off, 64);
    int lane = threadIdx.x & 63;
    int wid  = threadIdx.x >> 6;
    if (lane == 0) lds[wid] = v;
    __syncthreads();
    return lds[0] + lds[1] + lds[2] + lds[3];
}

// One thread per (b,t,hw); t lives in the LOW 3 lane bits so the thread
// holding (b,t-1,hw) is lane-1 -> temporal diffs via one __shfl per e.
// Every preds/target element is loaded exactly once (37.5 MB total).
// Two-kernel structure on purpose: R5/R6 showed that fusing the final
// reduction (atomics + threadfence tail) makes the allocator spill the
// cur[] working set (VGPR 20-24, 4-5x regression). No forced min-waves
// either (R5). Target: ~50 VGPR -> 8 waves/SIMD naturally.
__global__ __launch_bounds__(BLK) void crps_partial(const float* __restrict__ preds,
                                                    const float* __restrict__ target,
                                                    float* __restrict__ partials) {
    const int n  = blockIdx.x * BLK + threadIdx.x;   // 19 bits
    const int t  = n & 7;                            // lane bits [0,3)
    const int hw = (n >> 3) & (HW - 1);
    const int b  = n >> 18;

    const float* pb = preds + (size_t)((b * T_DIM + t) * E_DIM) * HW + hw;
    float cur[E_DIM];
#pragma unroll
    for (int e = 0; e < E_DIM; ++e)
        cur[e] = pb[(size_t)e * HW];
    const float tgt = target[(size_t)(b * T_DIM + t) * HW + hw];

    // temporal transition (t-1 -> t): pull previous-t value from lane-1
    const int lane = threadIdx.x & 63;
    const int src  = (lane > 0) ? (lane - 1) : 0;
    float tacc = 0.f;
#pragma unroll
    for (int e = 0; e < E_DIM; ++e) {
        float pv = __shfl(cur[e], src, 64);          // exec-sync, DS pipe
        if (t > 0)
            tacc += fabsf(cur[e] - pv);
    }

    // term1: sum_e |p_e - tgt|
    float t1 = 0.f;
#pragma unroll
    for (int e = 0; e < E_DIM; ++e)
        t1 += fabsf(cur[e] - tgt);
    // term2 core: sum_{i<j} |p_i - p_j|
    float s = 0.f;
#pragma unroll
    for (int i = 0; i < E_DIM; ++i)
#pragma unroll
        for (int j = i + 1; j < E_DIM; ++j)
            s += fabsf(cur[i] - cur[j]);

    // contribution of this (b,t,hw)
    float v = (t1 * (1.f / 16.f) - s * (1.f / 256.f)) * (1.f / 8.f)
            + tacc * (0.1f / 112.f);

    __shared__ float lds[4];
    float bsum = block_reduce_256(v, lds);
    if (threadIdx.x == 0)
        partials[blockIdx.x] = bsum;
}

__global__ __launch_bounds__(BLK) void crps_final(const float* __restrict__ partials,
                                                  float* __restrict__ out) {
    float v = 0.f;
#pragma unroll
    for (int i = 0; i < NBLK / BLK; ++i)            // 8 partials per thread
        v += partials[i * BLK + threadIdx.x];
    __shared__ float lds[4];
    float total = block_reduce_256(v, lds);
    if (threadIdx.x == 0)
        out[0] = total * (1.f / (float)NPOS);
}

extern "C" void kernel_launch(void* const* d_in, const int* in_sizes, int n_in,
                              void* d_out, int out_size, void* d_ws, size_t ws_size,
                              hipStream_t stream) {
    const float* preds  = (const float*)d_in[0];
    const float* target = (const float*)d_in[1];
    float* out      = (float*)d_out;
    float* partials = (float*)d_ws;   // 2048 floats = 8 KB scratch

    crps_partial<<<NBLK, BLK, 0, stream>>>(preds, target, partials);
    crps_final<<<1, BLK, 0, stream>>>(partials, out);
}